// Round 1
// baseline (98101.892 us; speedup 1.0000x reference)
//
#include <hip/hip_runtime.h>
#include <cstddef>
#include <cstdint>

#define T_INN 200
#define T_OUTT 400
#define BB 64
#define DENC 512
#define DRNN 1024
#define PREN 256
#define ATT 128
#define NFILT 32
#define KSZ 31
#define NMEL 80
#define NEGV -100000000.0f

__device__ __forceinline__ float sigf(float x) { return 1.0f / (1.0f + expf(-x)); }

// ---------------------------------------------------------------------------
// Generic tiled GEMM:  C[m][n] = act( sum_k A[m][k] * W[n][k] )
// grid.x = N/64, grid.y = M/64, block = 256. K multiple of 16.
// ---------------------------------------------------------------------------
__global__ __launch_bounds__(256) void gemm_pre_kernel(
    const float* __restrict__ A, int lda, const float* __restrict__ W, int ldw,
    float* __restrict__ C, int ldc, int K, int relu)
{
  __shared__ float As[16][66];
  __shared__ float Ws[16][66];
  const int tid = threadIdx.x;
  const int tn = tid & 15, tm = tid >> 4;
  const int n0 = blockIdx.x * 64;
  const int m0 = blockIdx.y * 64;
  float acc[4][4] = {{0.f}};
  for (int kt = 0; kt < K; kt += 16) {
#pragma unroll
    for (int i = 0; i < 4; i++) {
      int e = tid + 256 * i;
      int m = e >> 4, kk = e & 15;
      As[kk][m] = A[(size_t)(m0 + m) * lda + kt + kk];
    }
#pragma unroll
    for (int i = 0; i < 4; i++) {
      int e = tid + 256 * i;
      int n = e >> 4, kk = e & 15;
      Ws[kk][n] = W[(size_t)(n0 + n) * ldw + kt + kk];
    }
    __syncthreads();
#pragma unroll
    for (int kk = 0; kk < 16; kk++) {
      float2 a01 = *(const float2*)&As[kk][tm * 4];
      float2 a23 = *(const float2*)&As[kk][tm * 4 + 2];
      float2 w01 = *(const float2*)&Ws[kk][tn * 4];
      float2 w23 = *(const float2*)&Ws[kk][tn * 4 + 2];
      float a[4] = {a01.x, a01.y, a23.x, a23.y};
      float w[4] = {w01.x, w01.y, w23.x, w23.y};
#pragma unroll
      for (int mi = 0; mi < 4; mi++)
#pragma unroll
        for (int ni = 0; ni < 4; ni++)
          acc[mi][ni] = fmaf(a[mi], w[ni], acc[mi][ni]);
    }
    __syncthreads();
  }
#pragma unroll
  for (int mi = 0; mi < 4; mi++) {
    int m = m0 + tm * 4 + mi;
    float4 vv;
    vv.x = acc[mi][0]; vv.y = acc[mi][1]; vv.z = acc[mi][2]; vv.w = acc[mi][3];
    if (relu) {
      vv.x = fmaxf(vv.x, 0.f); vv.y = fmaxf(vv.y, 0.f);
      vv.z = fmaxf(vv.z, 0.f); vv.w = fmaxf(vv.w, 0.f);
    }
    *(float4*)&C[(size_t)m * ldc + n0 + tn * 4] = vv;
  }
}

// ---------------------------------------------------------------------------
// Per-step LSTM gate GEMM (M=64 batch), 3 concat segments, split-K partials.
// grid.x = 4096/64 = 64, grid.y = KSPLIT, block = 256.
// Cpart[ks][64][4096]. Segment boundaries multiples of 16.
// ---------------------------------------------------------------------------
struct GemmSegs {
  const float* A0; const float* W0; int lda0, ldw0, k0;
  const float* A1; const float* W1; int lda1, ldw1, k1;
  const float* A2; const float* W2; int lda2, ldw2, k2;
};

__global__ __launch_bounds__(256) void gemm_step_kernel(GemmSegs s, float* __restrict__ Cpart, int kChunk)
{
  __shared__ float As[16][66];
  __shared__ float Ws[16][66];
  const int tid = threadIdx.x;
  const int tn = tid & 15, tm = tid >> 4;
  const int n0 = blockIdx.x * 64;
  const int kbeg = blockIdx.y * kChunk;
  const int kend = kbeg + kChunk;
  const int b01 = s.k0, b12 = s.k0 + s.k1;
  float acc[4][4] = {{0.f}};
  for (int kt = kbeg; kt < kend; kt += 16) {
    const float *A, *W; int lda, ldw, ko;
    if (kt < b01)      { A = s.A0; W = s.W0; lda = s.lda0; ldw = s.ldw0; ko = kt; }
    else if (kt < b12) { A = s.A1; W = s.W1; lda = s.lda1; ldw = s.ldw1; ko = kt - b01; }
    else               { A = s.A2; W = s.W2; lda = s.lda2; ldw = s.ldw2; ko = kt - b12; }
#pragma unroll
    for (int i = 0; i < 4; i++) {
      int e = tid + 256 * i;
      int m = e >> 4, kk = e & 15;
      As[kk][m] = A[(size_t)m * lda + ko + kk];
    }
#pragma unroll
    for (int i = 0; i < 4; i++) {
      int e = tid + 256 * i;
      int n = e >> 4, kk = e & 15;
      Ws[kk][n] = W[(size_t)(n0 + n) * ldw + ko + kk];
    }
    __syncthreads();
#pragma unroll
    for (int kk = 0; kk < 16; kk++) {
      float2 a01 = *(const float2*)&As[kk][tm * 4];
      float2 a23 = *(const float2*)&As[kk][tm * 4 + 2];
      float2 w01 = *(const float2*)&Ws[kk][tn * 4];
      float2 w23 = *(const float2*)&Ws[kk][tn * 4 + 2];
      float a[4] = {a01.x, a01.y, a23.x, a23.y};
      float w[4] = {w01.x, w01.y, w23.x, w23.y};
#pragma unroll
      for (int mi = 0; mi < 4; mi++)
#pragma unroll
        for (int ni = 0; ni < 4; ni++)
          acc[mi][ni] = fmaf(a[mi], w[ni], acc[mi][ni]);
    }
    __syncthreads();
  }
  float* C = Cpart + (size_t)blockIdx.y * (64 * 4096);
#pragma unroll
  for (int mi = 0; mi < 4; mi++) {
    int m = tm * 4 + mi;
    float4 vv;
    vv.x = acc[mi][0]; vv.y = acc[mi][1]; vv.z = acc[mi][2]; vv.w = acc[mi][3];
    *(float4*)&C[(size_t)m * 4096 + n0 + tn * 4] = vv;
  }
}

// ---------------------------------------------------------------------------
// LSTM activation: sum 8 split-K partials + bias, gate math, update h, c.
// grid 256 x 256 threads = 65536 = 64 x 1024
// ---------------------------------------------------------------------------
__global__ __launch_bounds__(256) void lstm_act_kernel(
    const float* __restrict__ gp, const float* __restrict__ bias,
    float* __restrict__ h, float* __restrict__ c)
{
  int idx = blockIdx.x * 256 + threadIdx.x;
  int b = idx >> 10, j = idx & 1023;
  const float* g0 = gp + (size_t)b * 4096;
  float gi = bias[j], gf = bias[j + 1024], gg = bias[j + 2048], go = bias[j + 3072];
#pragma unroll
  for (int s = 0; s < 8; s++) {
    const float* g = g0 + (size_t)s * (64 * 4096);
    gi += g[j]; gf += g[j + 1024]; gg += g[j + 2048]; go += g[j + 3072];
  }
  float cn = sigf(gf) * c[idx] + sigf(gi) * tanhf(gg);
  c[idx] = cn;
  h[idx] = sigf(go) * tanhf(cn);
}

// pq[b][n] = sum_k ah[b][k] * Wq[n][k];  grid 32 x 256
__global__ __launch_bounds__(256) void pq_kernel(
    const float* __restrict__ h, const float* __restrict__ Wq, float* __restrict__ pq)
{
  int idx = blockIdx.x * 256 + threadIdx.x;
  int b = idx >> 7, n = idx & 127;
  const float4* hr = (const float4*)(h + (size_t)b * 1024);
  const float4* wr = (const float4*)(Wq + (size_t)n * 1024);
  float s = 0.f;
#pragma unroll 4
  for (int k = 0; k < 256; k++) {
    float4 a = hr[k], w = wr[k];
    s += a.x * w.x + a.y * w.y + a.z * w.z + a.w * w.w;
  }
  pq[idx] = s;
}

// ---------------------------------------------------------------------------
// Location-sensitive attention energies. One block per batch, 1024 threads:
// tid = g*256 + ti ; g in [0,4) splits filters (phase 1) and ATT dim (phase 2).
// ---------------------------------------------------------------------------
__global__ __launch_bounds__(1024) void energies_kernel(
    const float* __restrict__ aw, const float* __restrict__ awcum,
    const float* __restrict__ pq, const float* __restrict__ pmT,
    const float* __restrict__ Wconv, const float* __restrict__ Wloc,
    const float* __restrict__ vvec, const int* __restrict__ lens,
    float* __restrict__ energ)
{
  int b = blockIdx.x;
  int tid = threadIdx.x;
  int ti = tid & 255;
  int g = tid >> 8;
  __shared__ float aS[T_INN], cS[T_INN];
  __shared__ float convS[T_INN][33];
  __shared__ float ep[4][256];
  for (int i = tid; i < T_INN; i += 1024) {
    aS[i] = aw[b * T_INN + i];
    cS[i] = awcum[b * T_INN + i];
  }
  __syncthreads();
  if (ti < T_INN) {
#pragma unroll
    for (int f8 = 0; f8 < 8; f8++) {
      int f = g * 8 + f8;
      float s = 0.f;
#pragma unroll
      for (int k = 0; k < KSZ; k++) {
        int tt = ti + k - 15;
        if (tt >= 0 && tt < T_INN)
          s += Wconv[f * 62 + k] * aS[tt] + Wconv[f * 62 + 31 + k] * cS[tt];
      }
      convS[ti][f] = s;
    }
  }
  __syncthreads();
  float e = 0.f;
  if (ti < T_INN) {
#pragma unroll 2
    for (int aa = 0; aa < 32; aa++) {
      int a = g * 32 + aa;
      float x = pq[b * ATT + a] + pmT[((size_t)b * ATT + a) * T_INN + ti];
#pragma unroll
      for (int f = 0; f < NFILT; f++) x += Wloc[a * NFILT + f] * convS[ti][f];
      e += vvec[a] * tanhf(x);
    }
  }
  ep[g][ti] = e;
  __syncthreads();
  if (g == 0 && ti < T_INN) {
    float s = ep[0][ti] + ep[1][ti] + ep[2][ti] + ep[3][ti];
    if (ti >= lens[b]) s = NEGV;
    energ[b * T_INN + ti] = s;
  }
}

// ---------------------------------------------------------------------------
// Softmax over T_IN, write alignment output, update aw_cum, compute context.
// One block per batch, 256 threads.
// ---------------------------------------------------------------------------
__global__ __launch_bounds__(256) void softctx_kernel(
    const float* __restrict__ energ, const float* __restrict__ enc,
    float* __restrict__ aw, float* __restrict__ awcum,
    float* __restrict__ actx, float* __restrict__ alignsOut, int t)
{
  int b = blockIdx.x, tid = threadIdx.x;
  __shared__ float awS[T_INN];
  __shared__ float red[256];
  float e = (tid < T_INN) ? energ[b * T_INN + tid] : -3.0e38f;
  red[tid] = e;
  __syncthreads();
  for (int s = 128; s > 0; s >>= 1) {
    if (tid < s) red[tid] = fmaxf(red[tid], red[tid + s]);
    __syncthreads();
  }
  float mx = red[0];
  __syncthreads();
  float ex = (tid < T_INN) ? expf(e - mx) : 0.f;
  red[tid] = ex;
  __syncthreads();
  for (int s = 128; s > 0; s >>= 1) {
    if (tid < s) red[tid] += red[tid + s];
    __syncthreads();
  }
  float inv = 1.0f / red[0];
  if (tid < T_INN) {
    float a = ex * inv;
    awS[tid] = a;
    aw[b * T_INN + tid] = a;
    awcum[b * T_INN + tid] += a;
    alignsOut[(size_t)b * T_OUTT * T_INN + (size_t)t * T_INN + tid] = a;
  }
  __syncthreads();
  for (int e0 = tid; e0 < DENC; e0 += 256) {
    float s2 = 0.f;
#pragma unroll 4
    for (int tt = 0; tt < T_INN; tt++)
      s2 += awS[tt] * enc[((size_t)b * T_INN + tt) * DENC + e0];
    actx[b * DENC + e0] = s2;
  }
}

// out[b][m] = bp[m] + dh . Wp[m][:1024] + actx . Wp[m][1024:];  grid 20 x 256
__global__ __launch_bounds__(256) void outproj_kernel(
    const float* __restrict__ dh, const float* __restrict__ actx,
    const float* __restrict__ Wp, const float* __restrict__ bp,
    float* __restrict__ outsOut, int t)
{
  int idx = blockIdx.x * 256 + threadIdx.x;
  int b = idx / NMEL, m = idx - b * NMEL;
  float s = bp[m];
  const float4* w1 = (const float4*)(Wp + (size_t)m * 1536);
  const float4* h4 = (const float4*)(dh + (size_t)b * 1024);
#pragma unroll 4
  for (int k = 0; k < 256; k++) {
    float4 w = w1[k], a = h4[k];
    s += w.x * a.x + w.y * a.y + w.z * a.z + w.w * a.w;
  }
  const float4* w2 = (const float4*)(Wp + (size_t)m * 1536 + 1024);
  const float4* c4 = (const float4*)(actx + (size_t)b * 512);
#pragma unroll 4
  for (int k = 0; k < 128; k++) {
    float4 w = w2[k], a = c4[k];
    s += w.x * a.x + w.y * a.y + w.z * a.z + w.w * a.w;
  }
  outsOut[(size_t)b * T_OUTT * NMEL + (size_t)t * NMEL + m] = s;
}

// pm (b,t,a) -> pmT (b,a,t)
__global__ void transpose_pm_kernel(const float* __restrict__ pm, float* __restrict__ pmT)
{
  int b = blockIdx.z;
  int tT = blockIdx.x * 32, aT = blockIdx.y * 32;
  __shared__ float tile[32][33];
  int tx = threadIdx.x, ty = threadIdx.y;
#pragma unroll
  for (int i = 0; i < 4; i++) {
    int t = tT + ty + i * 8;
    int a = aT + tx;
    if (t < T_INN) tile[ty + i * 8][tx] = pm[((size_t)b * T_INN + t) * ATT + a];
  }
  __syncthreads();
#pragma unroll
  for (int i = 0; i < 4; i++) {
    int a = aT + ty + i * 8;
    int t = tT + tx;
    if (t < T_INN) pmT[((size_t)b * ATT + a) * T_INN + t] = tile[tx][ty + i * 8];
  }
}

extern "C" void kernel_launch(void* const* d_in, const int* in_sizes, int n_in,
                              void* d_out, int out_size, void* d_ws, size_t ws_size,
                              hipStream_t stream)
{
  const float* enc    = (const float*)d_in[0];
  const float* dec    = (const float*)d_in[1];
  const int*   lens   = (const int*)d_in[2];
  const float* W_p1   = (const float*)d_in[3];
  const float* W_p2   = (const float*)d_in[4];
  const float* W_ih_a = (const float*)d_in[5];
  const float* W_hh_a = (const float*)d_in[6];
  const float* b_a    = (const float*)d_in[7];
  const float* Wq     = (const float*)d_in[8];
  const float* Wmem   = (const float*)d_in[9];
  const float* vvec   = (const float*)d_in[10];
  const float* Wconv  = (const float*)d_in[11];
  const float* Wloc   = (const float*)d_in[12];
  const float* W_ih_d = (const float*)d_in[13];
  const float* W_hh_d = (const float*)d_in[14];
  const float* b_d    = (const float*)d_in[15];
  const float* Wp     = (const float*)d_in[16];
  const float* bp     = (const float*)d_in[17];

  float* ws = (float*)d_ws;
  size_t off = 0;
  float* xs  = ws + off; off += (size_t)25600 * 256;                 // (400,64,256)
  float* pmT = ws + off; off += (size_t)64 * 128 * 200;              // (b,a,t)
  float* ah = ws + off;                                              // states block
  float* ac    = ah + 65536;
  float* dh    = ac + 65536;
  float* dc    = dh + 65536;
  float* aw    = dc + 65536;          // 64*200
  float* awcum = aw + 12800;
  float* actx  = awcum + 12800;       // 64*512
  off += 4 * 65536 + 2 * 12800 + 32768;
  float* pq    = ws + off; off += 8192;
  float* energ = ws + off; off += 12800;
  // scratch region: precompute uses h1+pm_tmp; steps use ga+gd
  float* scratch = ws + off;
  float* h1  = scratch;                         // 25536*256
  float* pmt = scratch + (size_t)25536 * 256;   // 12800*128
  float* ga  = scratch;                         // 8*64*4096
  float* gd  = scratch + (size_t)8 * 64 * 4096;

  float* outsOut   = (float*)d_out;
  float* alignsOut = outsOut + (size_t)BB * T_OUTT * NMEL;

  // zero recurrent state + xs row block for t=0 (prenet of zero input = 0)
  hipMemsetAsync(ah, 0, (size_t)(4 * 65536 + 2 * 12800 + 32768) * sizeof(float), stream);
  hipMemsetAsync(xs, 0, (size_t)64 * 256 * sizeof(float), stream);

  // Precompute: prenet for steps 1..399 (xs[t] = prenet(dec[t-1]))
  gemm_pre_kernel<<<dim3(4, 399), 256, 0, stream>>>(dec, 80, W_p1, 80, h1, 256, 80, 1);
  gemm_pre_kernel<<<dim3(4, 399), 256, 0, stream>>>(h1, 256, W_p2, 256, xs + 64 * 256, 256, 256, 1);
  // processed memory + transpose to (b,a,t)
  gemm_pre_kernel<<<dim3(2, 200), 256, 0, stream>>>(enc, 512, Wmem, 512, pmt, 128, 512, 0);
  transpose_pm_kernel<<<dim3(7, 4, 64), dim3(32, 8), 0, stream>>>(pmt, pmT);

  for (int t = 0; t < T_OUTT; t++) {
    GemmSegs sa;
    sa.A0 = xs + (size_t)t * 64 * 256; sa.W0 = W_ih_a;       sa.lda0 = 256;  sa.ldw0 = 768;  sa.k0 = 256;
    sa.A1 = actx;                      sa.W1 = W_ih_a + 256; sa.lda1 = 512;  sa.ldw1 = 768;  sa.k1 = 512;
    sa.A2 = ah;                        sa.W2 = W_hh_a;       sa.lda2 = 1024; sa.ldw2 = 1024; sa.k2 = 1024;
    gemm_step_kernel<<<dim3(64, 8), 256, 0, stream>>>(sa, ga, 224);
    lstm_act_kernel<<<256, 256, 0, stream>>>(ga, b_a, ah, ac);
    pq_kernel<<<32, 256, 0, stream>>>(ah, Wq, pq);
    energies_kernel<<<64, 1024, 0, stream>>>(aw, awcum, pq, pmT, Wconv, Wloc, vvec, lens, energ);
    softctx_kernel<<<64, 256, 0, stream>>>(energ, enc, aw, awcum, actx, alignsOut, t);
    GemmSegs sd;
    sd.A0 = ah;   sd.W0 = W_ih_d;        sd.lda0 = 1024; sd.ldw0 = 1536; sd.k0 = 1024;
    sd.A1 = actx; sd.W1 = W_ih_d + 1024; sd.lda1 = 512;  sd.ldw1 = 1536; sd.k1 = 512;
    sd.A2 = dh;   sd.W2 = W_hh_d;        sd.lda2 = 1024; sd.ldw2 = 1024; sd.k2 = 1024;
    gemm_step_kernel<<<dim3(64, 8), 256, 0, stream>>>(sd, gd, 320);
    lstm_act_kernel<<<256, 256, 0, stream>>>(gd, b_d, dh, dc);
    outproj_kernel<<<20, 256, 0, stream>>>(dh, actx, Wp, bp, outsOut, t);
  }
}

// Round 2
// 69612.561 us; speedup vs baseline: 1.4093x; 1.4093x over previous
//
#include <hip/hip_runtime.h>
#include <cstddef>
#include <cstdint>

#define T_INN 200
#define T_OUTT 400
#define BB 64
#define DENC 512
#define NMEL 80

typedef unsigned short u16;
typedef __bf16 bf16x8 __attribute__((ext_vector_type(8)));
typedef float f32x4 __attribute__((ext_vector_type(4)));

__device__ __forceinline__ float sigf(float x) { return 1.0f / (1.0f + expf(-x)); }

// round-to-nearest-even f32 -> bf16
__device__ __forceinline__ u16 f2bf(float f) {
  unsigned u = __float_as_uint(f);
  unsigned r = u + 0x7fffu + ((u >> 16) & 1u);
  return (u16)(r >> 16);
}

__device__ __forceinline__ bf16x8 ldbf8(const u16* p) { return *(const bf16x8*)p; }

// ---------------------------------------------------------------------------
// fp32 tiled GEMM for precompute: C[m][n] = act(sum_k A[m][k]*W[n][k])
// grid.x = N/64, grid.y = M/64, block 256. Optional bf16 output.
// ---------------------------------------------------------------------------
__global__ __launch_bounds__(256) void gemm_pre_kernel(
    const float* __restrict__ A, int lda, const float* __restrict__ W, int ldw,
    float* __restrict__ C, u16* __restrict__ Cbf, int ldc, int K, int relu)
{
  __shared__ float As[16][66];
  __shared__ float Ws[16][66];
  const int tid = threadIdx.x;
  const int tn = tid & 15, tm = tid >> 4;
  const int n0 = blockIdx.x * 64;
  const int m0 = blockIdx.y * 64;
  float acc[4][4] = {{0.f}};
  for (int kt = 0; kt < K; kt += 16) {
#pragma unroll
    for (int i = 0; i < 4; i++) {
      int e = tid + 256 * i;
      int m = e >> 4, kk = e & 15;
      As[kk][m] = A[(size_t)(m0 + m) * lda + kt + kk];
    }
#pragma unroll
    for (int i = 0; i < 4; i++) {
      int e = tid + 256 * i;
      int n = e >> 4, kk = e & 15;
      Ws[kk][n] = W[(size_t)(n0 + n) * ldw + kt + kk];
    }
    __syncthreads();
#pragma unroll
    for (int kk = 0; kk < 16; kk++) {
      float2 a01 = *(const float2*)&As[kk][tm * 4];
      float2 a23 = *(const float2*)&As[kk][tm * 4 + 2];
      float2 w01 = *(const float2*)&Ws[kk][tn * 4];
      float2 w23 = *(const float2*)&Ws[kk][tn * 4 + 2];
      float a[4] = {a01.x, a01.y, a23.x, a23.y};
      float w[4] = {w01.x, w01.y, w23.x, w23.y};
#pragma unroll
      for (int mi = 0; mi < 4; mi++)
#pragma unroll
        for (int ni = 0; ni < 4; ni++)
          acc[mi][ni] = fmaf(a[mi], w[ni], acc[mi][ni]);
    }
    __syncthreads();
  }
#pragma unroll
  for (int mi = 0; mi < 4; mi++) {
    int m = m0 + tm * 4 + mi;
    float v0 = acc[mi][0], v1 = acc[mi][1], v2 = acc[mi][2], v3 = acc[mi][3];
    if (relu) {
      v0 = fmaxf(v0, 0.f); v1 = fmaxf(v1, 0.f);
      v2 = fmaxf(v2, 0.f); v3 = fmaxf(v3, 0.f);
    }
    if (Cbf) {
      u16* p = Cbf + (size_t)m * ldc + n0 + tn * 4;
      p[0] = f2bf(v0); p[1] = f2bf(v1); p[2] = f2bf(v2); p[3] = f2bf(v3);
    } else {
      float4 vv; vv.x = v0; vv.y = v1; vv.z = v2; vv.w = v3;
      *(float4*)&C[(size_t)m * ldc + n0 + tn * 4] = vv;
    }
  }
}

// ---------------------------------------------------------------------------
// Weight repack: W[n][k] fp32 -> bf16, MFMA B-fragment lane order.
// slot = (nt*KTtot + kt)*64 + lane ; element j: W[nt*16+(lane&15)][kt*32+(lane>>4)*8+j]
// ---------------------------------------------------------------------------
__global__ __launch_bounds__(256) void pack_w_kernel(
    const float* __restrict__ W, u16* __restrict__ P,
    int K, int KTl, int ktOff, int KTtot, int total)
{
  int slot = blockIdx.x * 256 + threadIdx.x;
  if (slot >= total) return;
  int lane = slot & 63;
  int ktl = (slot >> 6) % KTl;
  int nt = slot / (64 * KTl);
  int n = nt * 16 + (lane & 15);
  int k = ktl * 32 + (lane >> 4) * 8;
  const float* src = W + (size_t)n * K + k;
  u16 tmp[8];
#pragma unroll
  for (int i = 0; i < 8; i++) tmp[i] = f2bf(src[i]);
  u16* dst = P + ((size_t)(nt * KTtot + (ktl + ktOff)) * 64 + lane) * 8;
  *(uint4*)dst = *(const uint4*)tmp;
}

// ---------------------------------------------------------------------------
// bf16 MFMA gate GEMM: C[64][4096] partial over K-chunk.
// A = concat of 3 bf16 row-major segments (boundaries multiples of 32).
// B = packed weights. grid (64, 8), block 256 (4 waves, each: 1 n-tile x 4 m-tiles).
// ---------------------------------------------------------------------------
struct ASegs {
  const u16* A0; int lda0, k0;
  const u16* A1; int lda1, k1;
  const u16* A2; int lda2;
};

__global__ __launch_bounds__(256) void gates_mfma_kernel(
    ASegs s, const u16* __restrict__ Wpack, int KT, int nkt,
    float* __restrict__ Cpart)
{
  const int tid = threadIdx.x;
  const int w = tid >> 6, lane = tid & 63;
  const int ntile = blockIdx.x * 4 + w;
  const int kt0 = blockIdx.y * nkt;
  const int mrow = lane & 15;
  const int ksub = (lane >> 4) * 8;
  const int b01 = s.k0, b12 = s.k0 + s.k1;
  f32x4 acc0 = {0.f, 0.f, 0.f, 0.f};
  f32x4 acc1 = acc0, acc2 = acc0, acc3 = acc0;
  for (int kt = kt0; kt < kt0 + nkt; kt++) {
    int kb = kt * 32;
    const u16* Ap; int lda;
    if (kb < b01)      { Ap = s.A0; lda = s.lda0; }
    else if (kb < b12) { Ap = s.A1; lda = s.lda1; kb -= b01; }
    else               { Ap = s.A2; lda = s.lda2; kb -= b12; }
    const u16* abase = Ap + (size_t)mrow * lda + kb + ksub;
    bf16x8 bv = ldbf8(Wpack + ((size_t)(ntile * KT + kt) * 64 + lane) * 8);
    bf16x8 a0 = ldbf8(abase);
    bf16x8 a1 = ldbf8(abase + 16 * lda);
    bf16x8 a2 = ldbf8(abase + 32 * lda);
    bf16x8 a3 = ldbf8(abase + 48 * lda);
    acc0 = __builtin_amdgcn_mfma_f32_16x16x32_bf16(a0, bv, acc0, 0, 0, 0);
    acc1 = __builtin_amdgcn_mfma_f32_16x16x32_bf16(a1, bv, acc1, 0, 0, 0);
    acc2 = __builtin_amdgcn_mfma_f32_16x16x32_bf16(a2, bv, acc2, 0, 0, 0);
    acc3 = __builtin_amdgcn_mfma_f32_16x16x32_bf16(a3, bv, acc3, 0, 0, 0);
  }
  float* C = Cpart + (size_t)blockIdx.y * (64 * 4096);
  const int n = ntile * 16 + (lane & 15);
  const int rb = (lane >> 4) * 4;
#pragma unroll
  for (int r = 0; r < 4; r++) {
    C[(size_t)(0 + rb + r) * 4096 + n]  = acc0[r];
    C[(size_t)(16 + rb + r) * 4096 + n] = acc1[r];
    C[(size_t)(32 + rb + r) * 4096 + n] = acc2[r];
    C[(size_t)(48 + rb + r) * 4096 + n] = acc3[r];
  }
}

// ---------------------------------------------------------------------------
// LSTM activation: sum 8 split-K partials + bias, gates, update h,c; bf16 h.
// grid 256 x 256
// ---------------------------------------------------------------------------
__global__ __launch_bounds__(256) void lstm_act_kernel(
    const float* __restrict__ gp, const float* __restrict__ bias,
    float* __restrict__ h, float* __restrict__ c, u16* __restrict__ hbf)
{
  int idx = blockIdx.x * 256 + threadIdx.x;
  int b = idx >> 10, j = idx & 1023;
  const float* g0 = gp + (size_t)b * 4096;
  float gi = bias[j], gf = bias[j + 1024], gg = bias[j + 2048], go = bias[j + 3072];
#pragma unroll
  for (int s = 0; s < 8; s++) {
    const float* g = g0 + (size_t)s * (64 * 4096);
    gi += g[j]; gf += g[j + 1024]; gg += g[j + 2048]; go += g[j + 3072];
  }
  float cn = sigf(gf) * c[idx] + sigf(gi) * tanhf(gg);
  c[idx] = cn;
  float hn = sigf(go) * tanhf(cn);
  h[idx] = hn;
  hbf[idx] = f2bf(hn);
}

// ---------------------------------------------------------------------------
// Fused attention: pq + location conv + energies + mask + softmax + aligns +
// awcum update + context (fp32 & bf16). One block per batch, 1024 threads.
// ---------------------------------------------------------------------------
__global__ __launch_bounds__(1024) void att_kernel(
    const float* __restrict__ ah, float* __restrict__ aw, float* __restrict__ awcum,
    const float* __restrict__ pmT, const float* __restrict__ Wq,
    const float* __restrict__ Wconv, const float* __restrict__ Wloc,
    const float* __restrict__ vvec, const int* __restrict__ lens,
    const float* __restrict__ enc, float* __restrict__ actx, u16* __restrict__ actx_bf,
    float* __restrict__ alignsOut, int t)
{
  const int b = blockIdx.x, tid = threadIdx.x;
  const int g = tid >> 8, ti = tid & 255;
  __shared__ float aS[T_INN], cS[T_INN], ahS[1024];
  __shared__ float pp[128][9];
  __shared__ float pqS[128];
  __shared__ float convS[T_INN][33];
  __shared__ float ep[4][256];
  __shared__ float red[256];
  __shared__ float awS[256];
  __shared__ float cpart[1024];
  // phase 1: stage aw, awcum, ah
  if (tid < T_INN) { aS[tid] = aw[b * T_INN + tid]; cS[tid] = awcum[b * T_INN + tid]; }
  ahS[tid] = ah[(size_t)b * 1024 + tid];
  __syncthreads();
  // phase 2a: pq partials (a = tid>>3, k-chunk = tid&7)
  {
    int a = tid >> 3, kc = tid & 7;
    const float4* wv = (const float4*)(Wq + (size_t)a * 1024 + kc * 128);
    const float4* hv = (const float4*)(ahS + kc * 128);
    float s = 0.f;
#pragma unroll 8
    for (int i = 0; i < 32; i++) {
      float4 wq = wv[i], hh = hv[i];
      s += wq.x * hh.x + wq.y * hh.y + wq.z * hh.z + wq.w * hh.w;
    }
    pp[a][kc] = s;
  }
  __syncthreads();
  // phase 2b + 3: finish pq; location conv
  if (tid < 128) {
    float s = 0.f;
#pragma unroll
    for (int kc = 0; kc < 8; kc++) s += pp[tid][kc];
    pqS[tid] = s;
  }
  if (ti < T_INN) {
#pragma unroll
    for (int f8 = 0; f8 < 8; f8++) {
      int f = g * 8 + f8;
      float s = 0.f;
#pragma unroll
      for (int k = 0; k < 31; k++) {
        int tt = ti + k - 15;
        if (tt >= 0 && tt < T_INN)
          s += Wconv[f * 62 + k] * aS[tt] + Wconv[f * 62 + 31 + k] * cS[tt];
      }
      convS[ti][f] = s;
    }
  }
  __syncthreads();
  // phase 4: energies (ATT split 4 ways over g)
  float e = 0.f;
  if (ti < T_INN) {
    const float* pm = pmT + ((size_t)b * 128 + g * 32) * T_INN + ti;
#pragma unroll 4
    for (int aa = 0; aa < 32; aa++) {
      int a = g * 32 + aa;
      float x = pqS[a] + pm[(size_t)aa * T_INN];
      const float* wl = Wloc + a * 32;
#pragma unroll
      for (int f = 0; f < 32; f++) x += wl[f] * convS[ti][f];
      e += vvec[a] * tanhf(x);
    }
  }
  ep[g][ti] = e;
  __syncthreads();
  // phase 5: combine + mask + softmax
  float ev = -3.0e38f;
  if (tid < 256) {
    if (tid < T_INN) {
      ev = ep[0][tid] + ep[1][tid] + ep[2][tid] + ep[3][tid];
      if (tid >= lens[b]) ev = -100000000.0f;
    }
    red[tid] = ev;
  }
  __syncthreads();
  for (int s2 = 128; s2 > 0; s2 >>= 1) {
    if (tid < s2) red[tid] = fmaxf(red[tid], red[tid + s2]);
    __syncthreads();
  }
  float mx = red[0];
  __syncthreads();
  float ex = 0.f;
  if (tid < 256) { ex = (tid < T_INN) ? expf(ev - mx) : 0.f; red[tid] = ex; }
  __syncthreads();
  for (int s2 = 128; s2 > 0; s2 >>= 1) {
    if (tid < s2) red[tid] += red[tid + s2];
    __syncthreads();
  }
  float inv = 1.0f / red[0];
  if (tid < T_INN) {
    float a = ex * inv;
    awS[tid] = a;
    aw[b * T_INN + tid] = a;
    awcum[b * T_INN + tid] = cS[tid] + a;
    alignsOut[((size_t)b * T_OUTT + t) * T_INN + tid] = a;
  }
  __syncthreads();
  // phase 6: context = aw @ enc[b]
  {
    int e0 = tid & 511, half = tid >> 9;
    const float* ep2 = enc + ((size_t)b * T_INN + half * 100) * DENC + e0;
    float s = 0.f;
#pragma unroll 4
    for (int tt = 0; tt < 100; tt++) s += awS[half * 100 + tt] * ep2[(size_t)tt * DENC];
    cpart[tid] = s;
  }
  __syncthreads();
  if (tid < 512) {
    float v2 = cpart[tid] + cpart[512 + tid];
    actx[b * DENC + tid] = v2;
    actx_bf[b * DENC + tid] = f2bf(v2);
  }
}

// out[b][m] = bp[m] + dh.Wp[m][:1024] + actx.Wp[m][1024:];  grid 20 x 256
__global__ __launch_bounds__(256) void outproj_kernel(
    const float* __restrict__ dh, const float* __restrict__ actx,
    const float* __restrict__ Wp, const float* __restrict__ bp,
    float* __restrict__ outsOut, int t)
{
  int idx = blockIdx.x * 256 + threadIdx.x;
  int b = idx / NMEL, m = idx - b * NMEL;
  float s = bp[m];
  const float4* w1 = (const float4*)(Wp + (size_t)m * 1536);
  const float4* h4 = (const float4*)(dh + (size_t)b * 1024);
#pragma unroll 4
  for (int k = 0; k < 256; k++) {
    float4 w = w1[k], a = h4[k];
    s += w.x * a.x + w.y * a.y + w.z * a.z + w.w * a.w;
  }
  const float4* w2 = (const float4*)(Wp + (size_t)m * 1536 + 1024);
  const float4* c4 = (const float4*)(actx + (size_t)b * 512);
#pragma unroll 4
  for (int k = 0; k < 128; k++) {
    float4 w = w2[k], a = c4[k];
    s += w.x * a.x + w.y * a.y + w.z * a.z + w.w * a.w;
  }
  outsOut[((size_t)b * T_OUTT + t) * NMEL + m] = s;
}

// pm (b*t, a) -> pmT (b, a, t)
__global__ void transpose_pm_kernel(const float* __restrict__ pm, float* __restrict__ pmT)
{
  int b = blockIdx.z;
  int tT = blockIdx.x * 32, aT = blockIdx.y * 32;
  __shared__ float tile[32][33];
  int tx = threadIdx.x, ty = threadIdx.y;
#pragma unroll
  for (int i = 0; i < 4; i++) {
    int t = tT + ty + i * 8;
    int a = aT + tx;
    if (t < T_INN) tile[ty + i * 8][tx] = pm[((size_t)b * T_INN + t) * 128 + a];
  }
  __syncthreads();
#pragma unroll
  for (int i = 0; i < 4; i++) {
    int a = aT + ty + i * 8;
    int t = tT + tx;
    if (t < T_INN) pmT[((size_t)b * 128 + a) * T_INN + t] = tile[tx][ty + i * 8];
  }
}

extern "C" void kernel_launch(void* const* d_in, const int* in_sizes, int n_in,
                              void* d_out, int out_size, void* d_ws, size_t ws_size,
                              hipStream_t stream)
{
  const float* enc    = (const float*)d_in[0];
  const float* dec    = (const float*)d_in[1];
  const int*   lens   = (const int*)d_in[2];
  const float* W_p1   = (const float*)d_in[3];
  const float* W_p2   = (const float*)d_in[4];
  const float* W_ih_a = (const float*)d_in[5];
  const float* W_hh_a = (const float*)d_in[6];
  const float* b_a    = (const float*)d_in[7];
  const float* Wq     = (const float*)d_in[8];
  const float* Wmem   = (const float*)d_in[9];
  const float* vvec   = (const float*)d_in[10];
  const float* Wconv  = (const float*)d_in[11];
  const float* Wloc   = (const float*)d_in[12];
  const float* W_ih_d = (const float*)d_in[13];
  const float* W_hh_d = (const float*)d_in[14];
  const float* b_d    = (const float*)d_in[15];
  const float* Wp     = (const float*)d_in[16];
  const float* bp     = (const float*)d_in[17];

  float* ws = (float*)d_ws;
  size_t off = 0;
  u16* xs_bf = (u16*)(ws + off); off += (size_t)T_OUTT * 64 * 256 / 2;   // 3.28M fl
  float* pmT = ws + off; off += (size_t)64 * 128 * T_INN;                 // 1.64M fl
  u16* Wa_pack = (u16*)(ws + off); off += (size_t)4096 * 1792 / 2;        // 3.67M fl
  u16* Wd_pack = (u16*)(ws + off); off += (size_t)4096 * 2560 / 2;        // 5.24M fl
  // state block (zero-initialized): ah, ac, dh, dc, actx, aw, awcum, bf shadows
  float* stateBase = ws + off;
  float* ah    = stateBase;
  float* ac    = ah + 65536;
  float* dh    = ac + 65536;
  float* dc    = dh + 65536;
  float* actx  = dc + 65536;          // 64*512
  float* aw    = actx + 32768;        // 64*200
  float* awcum = aw + 12800;
  u16* ah_bf   = (u16*)(awcum + 12800);          // 65536 u16
  u16* dh_bf   = ah_bf + 65536;                  // 65536 u16
  u16* actx_bf = dh_bf + 65536;                  // 32768 u16
  size_t stateFloats = 4 * 65536 + 32768 + 2 * 12800 + (65536 + 65536 + 32768) / 2;
  off += stateFloats;
  float* scratch = ws + off;          // >= 6.54M floats: h1 / pmt (precompute), ga+gd (loop)
  float* h1 = scratch;                               // 399*64 x 256
  float* pmt = scratch;                              // reused after prenet (12800 x 128)
  float* ga = scratch;                               // 8*64*4096
  float* gd = scratch + (size_t)8 * 64 * 4096;

  float* outsOut   = (float*)d_out;
  float* alignsOut = outsOut + (size_t)BB * T_OUTT * NMEL;

  // zero recurrent state + t=0 prenet row (prenet(0)=0, no bias)
  hipMemsetAsync(stateBase, 0, stateFloats * sizeof(float), stream);
  hipMemsetAsync(xs_bf, 0, (size_t)64 * 256 * sizeof(u16), stream);

  // ---- precompute ----
  // pack weights: Wa = [W_ih_a | W_hh_a] (KT=56), Wd = [W_ih_d | W_hh_d] (KT=80)
  {
    int tot;
    tot = 256 * 24 * 64;
    pack_w_kernel<<<(tot + 255) / 256, 256, 0, stream>>>(W_ih_a, Wa_pack, 768, 24, 0, 56, tot);
    tot = 256 * 32 * 64;
    pack_w_kernel<<<(tot + 255) / 256, 256, 0, stream>>>(W_hh_a, Wa_pack, 1024, 32, 24, 56, tot);
    tot = 256 * 48 * 64;
    pack_w_kernel<<<(tot + 255) / 256, 256, 0, stream>>>(W_ih_d, Wd_pack, 1536, 48, 0, 80, tot);
    tot = 256 * 32 * 64;
    pack_w_kernel<<<(tot + 255) / 256, 256, 0, stream>>>(W_hh_d, Wd_pack, 1024, 32, 48, 80, tot);
  }
  // prenet (steps 1..399): h1 = relu(dec @ Wp1^T); xs_bf[1:] = relu(h1 @ Wp2^T)
  gemm_pre_kernel<<<dim3(4, 399), 256, 0, stream>>>(dec, 80, W_p1, 80, h1, nullptr, 256, 80, 1);
  gemm_pre_kernel<<<dim3(4, 399), 256, 0, stream>>>(h1, 256, W_p2, 256, nullptr, xs_bf + 64 * 256, 256, 256, 1);
  // processed memory -> (b,a,t)
  gemm_pre_kernel<<<dim3(2, 200), 256, 0, stream>>>(enc, 512, Wmem, 512, pmt, nullptr, 128, 512, 0);
  transpose_pm_kernel<<<dim3(7, 4, 64), dim3(32, 8), 0, stream>>>(pmt, pmT);

  // ---- decode loop ----
  for (int t = 0; t < T_OUTT; t++) {
    ASegs sa;
    sa.A0 = xs_bf + (size_t)t * 64 * 256; sa.lda0 = 256;  sa.k0 = 256;
    sa.A1 = actx_bf;                      sa.lda1 = 512;  sa.k1 = 512;
    sa.A2 = ah_bf;                        sa.lda2 = 1024;
    gates_mfma_kernel<<<dim3(64, 8), 256, 0, stream>>>(sa, Wa_pack, 56, 7, ga);
    lstm_act_kernel<<<256, 256, 0, stream>>>(ga, b_a, ah, ac, ah_bf);
    att_kernel<<<64, 1024, 0, stream>>>(ah, aw, awcum, pmT, Wq, Wconv, Wloc, vvec,
                                        lens, enc, actx, actx_bf, alignsOut, t);
    ASegs sd;
    sd.A0 = ah_bf;   sd.lda0 = 1024; sd.k0 = 1024;
    sd.A1 = actx_bf; sd.lda1 = 512;  sd.k1 = 512;
    sd.A2 = dh_bf;   sd.lda2 = 1024;
    gates_mfma_kernel<<<dim3(64, 8), 256, 0, stream>>>(sd, Wd_pack, 80, 10, gd);
    lstm_act_kernel<<<256, 256, 0, stream>>>(gd, b_d, dh, dc, dh_bf);
    outproj_kernel<<<20, 256, 0, stream>>>(dh, actx, Wp, bp, outsOut, t);
  }
}